// Round 8
// baseline (125.477 us; speedup 1.0000x reference)
//
#include <hip/hip_runtime.h>

#define IMG 8
#define LH 150
#define LQ 10
#define KITER 10   // 9 scan steps + final conv
#define ROW (IMG * IMG + 2)   // 66 floats per batch row

// ds_bpermute with precomputed BYTE address. Full-wave convergence required.
// Used once per item at the end (sel-lane broadcast).
__device__ __forceinline__ float bperm(int byte_addr, float v) {
    return __builtin_bit_cast(float,
        __builtin_amdgcn_ds_bpermute(byte_addr, __builtin_bit_cast(int, v)));
}

// Force a wave-uniform value into an SGPR (scan-weight pinning).
__device__ __forceinline__ float rfl(float v) {
    return __builtin_bit_cast(float,
        __builtin_amdgcn_readfirstlane(__builtin_bit_cast(int, v)));
}

// Static lane swizzle: new_lane = lane ^ 24 within each 32-lane group
// (BitMode offset = (24<<10)|0x1F = 0x601F). Crosses the 16-lane DPP row
// for the y=3 <-> y=4 vertical taps. Full convergence required.
__device__ __forceinline__ float swz24(float v) {
    return __builtin_bit_cast(float,
        __builtin_amdgcn_ds_swizzle(__builtin_bit_cast(int, v), 0x601F));
}

// DPP lane shift within 16-lane rows, bound_ctrl=1 (out-of-bounds -> 0.0).
template <int CTRL>
__device__ __forceinline__ float dppf(float v) {
    return __builtin_bit_cast(float,
        __builtin_amdgcn_update_dpp(0, __builtin_bit_cast(int, v),
                                    CTRL, 0xF, 0xF, true));
}
#define DPP_SHR1 0x111   // lane i <- i-1  (x-1)
#define DPP_SHL1 0x101   // lane i <- i+1  (x+1)
#define DPP_SHR8 0x118   // lane i <- i-8  (valid i%16>=8, else 0)
#define DPP_SHL8 0x108   // lane i <- i+8  (valid i%16<8, else 0)

// ---------------------------------------------------------------------------
// Pre-kernel: collapse h/r convs (exact — no nonlinearity between h and r).
// Own dispatch: both regalloc-pathology builds (R5/R7, VGPR_Count=28, remat
// bloat) had this reduction FUSED into vin; the clean builds had it here.
// ---------------------------------------------------------------------------
__global__ void weff_kernel(const float* __restrict__ Wh,
                            const float* __restrict__ bh,
                            const float* __restrict__ Wr,
                            float* __restrict__ ws) {
    const int wv = threadIdx.x >> 6;   // 0..9 (wave-uniform)
    const int lane = threadIdx.x & 63;
    float partial = 0.f;
    for (int c = lane; c < LH; c += 64) {
        const float wr = Wr[c];
        partial += wr * ((wv < 9) ? Wh[c * 9 + wv] : bh[c]);
    }
    #pragma unroll
    for (int off = 32; off > 0; off >>= 1)
        partial += __shfl_xor(partial, off);   // full wave active
    if (lane == 0) ws[wv] = partial;
}

// ---------------------------------------------------------------------------
// Main kernel. Round-15 = R6's verified base (2-item/32-lane layout, SGPR-
// pinned scan weights, separate weff) with three deltas:
//  (1) __launch_bounds__(256, 8): deconfound the R5/R7 pathology — if the
//      trigger was the fused weff loop (hypothesis), this clean kernel at
//      min-waves=8 should allocate 40-64 VGPRs and run 8 waves/SIMD
//      (R6 was 6), closing part of the latency-hiding gap.
//  (2) channel-max grouped in triples -> v_max3_f32 fusion: 9 -> 5 max ops
//      per r per step (exact: max over a set is order-invariant).
//  (3) sel coords/one-hot recomputed in the epilogue (2 reloads) instead of
//      held live across the scan (-4 regs on the scan live set).
// Layout (verified R5-R7): lane = item*32 + h*16 + q*8 + x; register r
// holds row y = h*4 + 2r + q. Vertical taps = row_shr:8/row_shl:8 DPP sums
// (exactly one term nonzero); the y=3<->4 crossing is one static ds_swizzle
// (lane^24) per source reg: 2 DS ops per scan step.
// ---------------------------------------------------------------------------
__global__ __launch_bounds__(256, 8) void vin_kernel(
    const float* __restrict__ S,
    const float* __restrict__ Wq,
    const float* __restrict__ w,
    const float* __restrict__ Wfc,
    const float* __restrict__ ws,
    float* __restrict__ out,
    int B) {
    const int wave = threadIdx.x >> 6;
    const int lane = threadIdx.x & 63;
    const long b0 = (long)(blockIdx.x * 4 + wave) * 2;   // items b0, b0+1
    if (b0 >= B) return;                                  // wave-uniform

    const int item = lane >> 5;        // 0,1
    const int l32  = lane & 31;
    const int h    = l32 >> 4;         // y half (0: y=0..3, 1: y=4..7)
    const int q    = (l32 >> 3) & 1;   // row parity within half
    const int x    = l32 & 7;

    const float mskL = (x > 0) ? 1.f : 0.f;
    const float mskR = (x < 7) ? 1.f : 0.f;
    const float m3   = (h == 1 && q == 0) ? 1.f : 0.f;  // consumers of y=3 via swz
    const float m4   = (h == 0 && q == 1) ? 1.f : 0.f;  // consumers of y=4 via swz

    // ---- per-item state (sel coords deferred to epilogue)
    const float* Sb = S + (b0 + item) * ROW;
    float v[2];
    v[0] = Sb[(h * 4 + q) * 8 + x];        // y = h4 + q     (r=0)
    v[1] = Sb[(h * 4 + 2 + q) * 8 + x];    // y = h4 + 2 + q (r=1)

    // Build the 5 window rows d[j] = grid row (h4+q + j-1), j=0..4, and the
    // x-shifted copies. Output r uses rows d[2r..2r+2].
    auto rows5 = [&](const float vv[2], float d[5]) {
        const float X3 = swz24(vv[1]);   // y=3 -> lanes (h1,q0)
        const float X4 = swz24(vv[0]);   // y=4 -> lanes (h0,q1)
        d[1] = vv[0];
        d[3] = vv[1];
        d[2] = dppf<DPP_SHL8>(vv[0]) + dppf<DPP_SHR8>(vv[1]);
        d[0] = fmaf(X3, m3, dppf<DPP_SHR8>(vv[0]));
        d[4] = fmaf(X4, m4, dppf<DPP_SHL8>(vv[1]));
    };
    auto lcr = [&](const float d[5], float L[5], float R[5]) {
        #pragma unroll
        for (int j = 0; j < 5; ++j) {
            L[j] = mskL * dppf<DPP_SHR1>(d[j]);
            R[j] = mskR * dppf<DPP_SHL1>(d[j]);
        }
    };

    // --- r = conv(X, Weff, pad=1) + beff  (in place: v becomes r)
    {
        float d[5], L[5], R[5];
        rows5(v, d); lcr(d, L, R);
        const float bias = ws[9];
        #pragma unroll
        for (int r = 0; r < 2; ++r) {
            float a = bias;
            #pragma unroll
            for (int ky = 0; ky < 3; ++ky) {
                const int j = 2 * r + ky;
                a = fmaf(L[j], ws[ky * 3 + 0], a);
                a = fmaf(d[j], ws[ky * 3 + 1], a);
                a = fmaf(R[j], ws[ky * 3 + 2], a);
            }
            v[r] = a;   // d/L/R already captured old v
        }
    }

    // --- qr[o] = conv(r, Wq, pad=1) — loop-invariant across the scan.
    float qr[LQ][2];
    {
        float d[5], L[5], R[5];
        rows5(v, d); lcr(d, L, R);
        #pragma unroll
        for (int o = 0; o < LQ; ++o)
            #pragma unroll
            for (int r = 0; r < 2; ++r) {
                float a = L[2 * r] * Wq[o * 9 + 0];
                a = fmaf(d[2 * r],     Wq[o * 9 + 1], a);
                a = fmaf(R[2 * r],     Wq[o * 9 + 2], a);
                a = fmaf(L[2 * r + 1], Wq[o * 9 + 3], a);
                a = fmaf(d[2 * r + 1], Wq[o * 9 + 4], a);
                a = fmaf(R[2 * r + 1], Wq[o * 9 + 5], a);
                a = fmaf(L[2 * r + 2], Wq[o * 9 + 6], a);
                a = fmaf(d[2 * r + 2], Wq[o * 9 + 7], a);
                a = fmaf(R[2 * r + 2], Wq[o * 9 + 8], a);
                qr[o][r] = a;
            }
    }

    // Pin the 90 scan weights to SGPRs (one-time; scan body then has only
    // 2 ds_swizzle + VALU).
    float wu[LQ][9];
    #pragma unroll
    for (int o = 0; o < LQ; ++o)
        #pragma unroll
        for (int t = 0; t < 9; ++t)
            wu[o][t] = rfl(w[o * 9 + t]);

    // v = max over channels of qr (max3-fusable tree)
    #pragma unroll
    for (int r = 0; r < 2; ++r) {
        const float g0 = fmaxf(fmaxf(qr[0][r], qr[1][r]), qr[2][r]);
        const float g1 = fmaxf(fmaxf(qr[3][r], qr[4][r]), qr[5][r]);
        const float g2 = fmaxf(fmaxf(qr[6][r], qr[7][r]), qr[8][r]);
        v[r] = fmaxf(fmaxf(g0, g1), fmaxf(g2, qr[9][r]));
    }

    // Per-channel conv result for register row r (taps in verified order).
    auto chan = [&](const float d[5], const float L[5], const float R[5],
                    int o, int r) {
        float a = qr[o][r];
        a = fmaf(L[2 * r],     wu[o][0], a);
        a = fmaf(d[2 * r],     wu[o][1], a);
        a = fmaf(R[2 * r],     wu[o][2], a);
        a = fmaf(L[2 * r + 1], wu[o][3], a);
        a = fmaf(d[2 * r + 1], wu[o][4], a);
        a = fmaf(R[2 * r + 1], wu[o][5], a);
        a = fmaf(L[2 * r + 2], wu[o][6], a);
        a = fmaf(d[2 * r + 2], wu[o][7], a);
        a = fmaf(R[2 * r + 2], wu[o][8], a);
        return a;
    };

    // --- 9 scan steps: 2 ds_swizzle + DPP taps + 180 fma + max3 trees.
    #pragma unroll 3
    for (int k = 0; k < KITER - 1; ++k) {
        float d[5], L[5], R[5];
        rows5(v, d); lcr(d, L, R);
        #pragma unroll
        for (int r = 0; r < 2; ++r) {
            const float g0 = fmaxf(fmaxf(chan(d, L, R, 0, r),
                                         chan(d, L, R, 1, r)),
                                   chan(d, L, R, 2, r));
            const float g1 = fmaxf(fmaxf(chan(d, L, R, 3, r),
                                         chan(d, L, R, 4, r)),
                                   chan(d, L, R, 5, r));
            const float g2 = fmaxf(fmaxf(chan(d, L, R, 6, r),
                                         chan(d, L, R, 7, r)),
                                   chan(d, L, R, 8, r));
            v[r] = fmaxf(fmaxf(g0, g1), fmaxf(g2, chan(d, L, R, 9, r)));
        }
    }

    // --- Epilogue: final conv fused with sel extraction + Wfc dot.
    // sel coords recomputed here (kept out of the scan live set).
    const long b = b0 + item;
    const float* Sb2 = S + b * ROW;
    const int s1i = (int)Sb2[IMG * IMG];
    const int s2i = (int)Sb2[IMG * IMG + 1];
    // lane holding (s1,s2): y=s1 -> h=s1>>2, q=s1&1, reg r=(s1>>1)&1
    const int selAddr = ((item << 5) + ((s1i >> 2) << 4) + ((s1i & 1) << 3) + s2i) << 2;
    const float e0 = (((s1i >> 1) & 1) == 0) ? 1.f : 0.f;
    const float e1 = 1.f - e0;
    const int row = l32 & 7;
    float osum = 0.f;
    {
        float d[5], L[5], R[5];
        rows5(v, d); lcr(d, L, R);
        #pragma unroll
        for (int o = 0; o < LQ; ++o) {
            const float a0 = chan(d, L, R, o, 0);
            const float a1 = chan(d, L, R, o, 1);
            float t = a0 * e0;
            t = fmaf(a1, e1, t);                  // one-hot reg select (exact)
            const float qs = bperm(selAddr, t);   // full convergence
            osum = fmaf(qs, Wfc[row * LQ + o], osum);
        }
    }
    // lanes 0..7 of each 32-lane item group emit that item's 8 logits
    if (l32 < 8) out[b * 8 + row] = osum;
}

extern "C" void kernel_launch(void* const* d_in, const int* in_sizes, int n_in,
                              void* d_out, int out_size, void* d_ws, size_t ws_size,
                              hipStream_t stream) {
    const float* S   = (const float*)d_in[0];
    const float* Wh  = (const float*)d_in[1];
    const float* bh  = (const float*)d_in[2];
    const float* Wr  = (const float*)d_in[3];
    const float* Wq  = (const float*)d_in[4];
    const float* w   = (const float*)d_in[5];
    const float* Wfc = (const float*)d_in[6];
    float* out = (float*)d_out;
    float* ws  = (float*)d_ws;

    const int B = in_sizes[0] / ROW;

    weff_kernel<<<1, 640, 0, stream>>>(Wh, bh, Wr, ws);

    // 4 waves/block, 2 items/wave => 8 items per block.
    const int grid = (B + 7) / 8;
    vin_kernel<<<grid, 256, 0, stream>>>(S, Wq, w, Wfc, ws, out, B);
}

// Round 9
// 99.139 us; speedup vs baseline: 1.2657x; 1.2657x over previous
//
#include <hip/hip_runtime.h>

#define IMG 8
#define LH 150
#define LQ 10
#define KITER 10   // 9 scan steps + final conv
#define ROW (IMG * IMG + 2)   // 66 floats per batch row

// ds_bpermute with precomputed BYTE address. Full-wave convergence required.
// Used once per item at the end (sel-lane broadcast).
__device__ __forceinline__ float bperm(int byte_addr, float v) {
    return __builtin_bit_cast(float,
        __builtin_amdgcn_ds_bpermute(byte_addr, __builtin_bit_cast(int, v)));
}

// Force a wave-uniform value into an SGPR (scan-weight pinning).
__device__ __forceinline__ float rfl(float v) {
    return __builtin_bit_cast(float,
        __builtin_amdgcn_readfirstlane(__builtin_bit_cast(int, v)));
}

// Static lane swizzle: new_lane = lane ^ 24 within each 32-lane group
// (BitMode offset = (24<<10)|0x1F = 0x601F). Crosses the 16-lane DPP row
// for the y=3 <-> y=4 vertical taps. Full convergence required.
__device__ __forceinline__ float swz24(float v) {
    return __builtin_bit_cast(float,
        __builtin_amdgcn_ds_swizzle(__builtin_bit_cast(int, v), 0x601F));
}

// DPP lane shift within 16-lane rows, bound_ctrl=1 (out-of-bounds -> 0.0).
template <int CTRL>
__device__ __forceinline__ float dppf(float v) {
    return __builtin_bit_cast(float,
        __builtin_amdgcn_update_dpp(0, __builtin_bit_cast(int, v),
                                    CTRL, 0xF, 0xF, true));
}
#define DPP_SHR1 0x111   // lane i <- i-1  (x-1)
#define DPP_SHL1 0x101   // lane i <- i+1  (x+1)
#define DPP_SHR8 0x118   // lane i <- i-8  (valid i%16>=8, else 0)
#define DPP_SHL8 0x108   // lane i <- i+8  (valid i%16<8, else 0)

// ---------------------------------------------------------------------------
// Pre-kernel: collapse h/r convs (exact — no nonlinearity between h and r).
// Kept as its own dispatch (fusing it was NOT the pathology trigger, but it
// costs nothing here and keeps vin's regalloc context minimal).
// ---------------------------------------------------------------------------
__global__ void weff_kernel(const float* __restrict__ Wh,
                            const float* __restrict__ bh,
                            const float* __restrict__ Wr,
                            float* __restrict__ ws) {
    const int wv = threadIdx.x >> 6;   // 0..9 (wave-uniform)
    const int lane = threadIdx.x & 63;
    float partial = 0.f;
    for (int c = lane; c < LH; c += 64) {
        const float wr = Wr[c];
        partial += wr * ((wv < 9) ? Wh[c * 9 + wv] : bh[c]);
    }
    #pragma unroll
    for (int off = 32; off > 0; off >>= 1)
        partial += __shfl_xor(partial, off);   // full wave active
    if (lane == 0) ws[wv] = partial;
}

// ---------------------------------------------------------------------------
// Main kernel. Round-16: __launch_bounds__(256, 6) — REVERT of the R7/R8
// experiment. Evidence across R5/R7/R8: min-waves >= 7 collapses regalloc
// (VGPR_Count=28, SGPR target shrinks 112->80 so the 90 SGPR-pinned weights
// no longer fit, remat bloat ~1.6x instructions, vin 64us). (256,6) is the
// proven-clean setting (R2: VGPR=36; R6: vin<40us). Kept from R8:
//  - channel-max in triples -> v_max3_f32 (9 -> 5 max ops per r per step);
//  - sel coords/one-hot recomputed in the epilogue (smaller scan live set —
//    helps the natural allocation land <= 64 VGPR = 8 waves/SIMD).
// Layout (verified R5-R8): lane = item*32 + h*16 + q*8 + x; register r
// holds row y = h*4 + 2r + q. Vertical taps = row_shr:8/row_shl:8 DPP sums
// (exactly one term nonzero); the y=3<->4 crossing is one static ds_swizzle
// (lane^24) per source reg: 2 DS ops per scan step.
// ---------------------------------------------------------------------------
__global__ __launch_bounds__(256, 6) void vin_kernel(
    const float* __restrict__ S,
    const float* __restrict__ Wq,
    const float* __restrict__ w,
    const float* __restrict__ Wfc,
    const float* __restrict__ ws,
    float* __restrict__ out,
    int B) {
    const int wave = threadIdx.x >> 6;
    const int lane = threadIdx.x & 63;
    const long b0 = (long)(blockIdx.x * 4 + wave) * 2;   // items b0, b0+1
    if (b0 >= B) return;                                  // wave-uniform

    const int item = lane >> 5;        // 0,1
    const int l32  = lane & 31;
    const int h    = l32 >> 4;         // y half (0: y=0..3, 1: y=4..7)
    const int q    = (l32 >> 3) & 1;   // row parity within half
    const int x    = l32 & 7;

    const float mskL = (x > 0) ? 1.f : 0.f;
    const float mskR = (x < 7) ? 1.f : 0.f;
    const float m3   = (h == 1 && q == 0) ? 1.f : 0.f;  // consumers of y=3 via swz
    const float m4   = (h == 0 && q == 1) ? 1.f : 0.f;  // consumers of y=4 via swz

    // ---- per-item state (sel coords deferred to epilogue)
    const float* Sb = S + (b0 + item) * ROW;
    float v[2];
    v[0] = Sb[(h * 4 + q) * 8 + x];        // y = h4 + q     (r=0)
    v[1] = Sb[(h * 4 + 2 + q) * 8 + x];    // y = h4 + 2 + q (r=1)

    // Build the 5 window rows d[j] = grid row (h4+q + j-1), j=0..4, and the
    // x-shifted copies. Output r uses rows d[2r..2r+2].
    auto rows5 = [&](const float vv[2], float d[5]) {
        const float X3 = swz24(vv[1]);   // y=3 -> lanes (h1,q0)
        const float X4 = swz24(vv[0]);   // y=4 -> lanes (h0,q1)
        d[1] = vv[0];
        d[3] = vv[1];
        d[2] = dppf<DPP_SHL8>(vv[0]) + dppf<DPP_SHR8>(vv[1]);
        d[0] = fmaf(X3, m3, dppf<DPP_SHR8>(vv[0]));
        d[4] = fmaf(X4, m4, dppf<DPP_SHL8>(vv[1]));
    };
    auto lcr = [&](const float d[5], float L[5], float R[5]) {
        #pragma unroll
        for (int j = 0; j < 5; ++j) {
            L[j] = mskL * dppf<DPP_SHR1>(d[j]);
            R[j] = mskR * dppf<DPP_SHL1>(d[j]);
        }
    };

    // --- r = conv(X, Weff, pad=1) + beff  (in place: v becomes r)
    {
        float d[5], L[5], R[5];
        rows5(v, d); lcr(d, L, R);
        const float bias = ws[9];
        #pragma unroll
        for (int r = 0; r < 2; ++r) {
            float a = bias;
            #pragma unroll
            for (int ky = 0; ky < 3; ++ky) {
                const int j = 2 * r + ky;
                a = fmaf(L[j], ws[ky * 3 + 0], a);
                a = fmaf(d[j], ws[ky * 3 + 1], a);
                a = fmaf(R[j], ws[ky * 3 + 2], a);
            }
            v[r] = a;   // d/L/R already captured old v
        }
    }

    // --- qr[o] = conv(r, Wq, pad=1) — loop-invariant across the scan.
    float qr[LQ][2];
    {
        float d[5], L[5], R[5];
        rows5(v, d); lcr(d, L, R);
        #pragma unroll
        for (int o = 0; o < LQ; ++o)
            #pragma unroll
            for (int r = 0; r < 2; ++r) {
                float a = L[2 * r] * Wq[o * 9 + 0];
                a = fmaf(d[2 * r],     Wq[o * 9 + 1], a);
                a = fmaf(R[2 * r],     Wq[o * 9 + 2], a);
                a = fmaf(L[2 * r + 1], Wq[o * 9 + 3], a);
                a = fmaf(d[2 * r + 1], Wq[o * 9 + 4], a);
                a = fmaf(R[2 * r + 1], Wq[o * 9 + 5], a);
                a = fmaf(L[2 * r + 2], Wq[o * 9 + 6], a);
                a = fmaf(d[2 * r + 2], Wq[o * 9 + 7], a);
                a = fmaf(R[2 * r + 2], Wq[o * 9 + 8], a);
                qr[o][r] = a;
            }
    }

    // Pin the 90 scan weights to SGPRs (one-time; scan body then has only
    // 2 ds_swizzle + VALU).
    float wu[LQ][9];
    #pragma unroll
    for (int o = 0; o < LQ; ++o)
        #pragma unroll
        for (int t = 0; t < 9; ++t)
            wu[o][t] = rfl(w[o * 9 + t]);

    // v = max over channels of qr (max3-fusable tree)
    #pragma unroll
    for (int r = 0; r < 2; ++r) {
        const float g0 = fmaxf(fmaxf(qr[0][r], qr[1][r]), qr[2][r]);
        const float g1 = fmaxf(fmaxf(qr[3][r], qr[4][r]), qr[5][r]);
        const float g2 = fmaxf(fmaxf(qr[6][r], qr[7][r]), qr[8][r]);
        v[r] = fmaxf(fmaxf(g0, g1), fmaxf(g2, qr[9][r]));
    }

    // Per-channel conv result for register row r (taps in verified order).
    auto chan = [&](const float d[5], const float L[5], const float R[5],
                    int o, int r) {
        float a = qr[o][r];
        a = fmaf(L[2 * r],     wu[o][0], a);
        a = fmaf(d[2 * r],     wu[o][1], a);
        a = fmaf(R[2 * r],     wu[o][2], a);
        a = fmaf(L[2 * r + 1], wu[o][3], a);
        a = fmaf(d[2 * r + 1], wu[o][4], a);
        a = fmaf(R[2 * r + 1], wu[o][5], a);
        a = fmaf(L[2 * r + 2], wu[o][6], a);
        a = fmaf(d[2 * r + 2], wu[o][7], a);
        a = fmaf(R[2 * r + 2], wu[o][8], a);
        return a;
    };

    // --- 9 scan steps: 2 ds_swizzle + DPP taps + 180 fma + max3 trees.
    #pragma unroll 3
    for (int k = 0; k < KITER - 1; ++k) {
        float d[5], L[5], R[5];
        rows5(v, d); lcr(d, L, R);
        #pragma unroll
        for (int r = 0; r < 2; ++r) {
            const float g0 = fmaxf(fmaxf(chan(d, L, R, 0, r),
                                         chan(d, L, R, 1, r)),
                                   chan(d, L, R, 2, r));
            const float g1 = fmaxf(fmaxf(chan(d, L, R, 3, r),
                                         chan(d, L, R, 4, r)),
                                   chan(d, L, R, 5, r));
            const float g2 = fmaxf(fmaxf(chan(d, L, R, 6, r),
                                         chan(d, L, R, 7, r)),
                                   chan(d, L, R, 8, r));
            v[r] = fmaxf(fmaxf(g0, g1), fmaxf(g2, chan(d, L, R, 9, r)));
        }
    }

    // --- Epilogue: final conv fused with sel extraction + Wfc dot.
    // sel coords recomputed here (kept out of the scan live set).
    const long b = b0 + item;
    const float* Sb2 = S + b * ROW;
    const int s1i = (int)Sb2[IMG * IMG];
    const int s2i = (int)Sb2[IMG * IMG + 1];
    // lane holding (s1,s2): y=s1 -> h=s1>>2, q=s1&1, reg r=(s1>>1)&1
    const int selAddr = ((item << 5) + ((s1i >> 2) << 4) + ((s1i & 1) << 3) + s2i) << 2;
    const float e0 = (((s1i >> 1) & 1) == 0) ? 1.f : 0.f;
    const float e1 = 1.f - e0;
    const int row = l32 & 7;
    float osum = 0.f;
    {
        float d[5], L[5], R[5];
        rows5(v, d); lcr(d, L, R);
        #pragma unroll
        for (int o = 0; o < LQ; ++o) {
            const float a0 = chan(d, L, R, o, 0);
            const float a1 = chan(d, L, R, o, 1);
            float t = a0 * e0;
            t = fmaf(a1, e1, t);                  // one-hot reg select (exact)
            const float qs = bperm(selAddr, t);   // full convergence
            osum = fmaf(qs, Wfc[row * LQ + o], osum);
        }
    }
    // lanes 0..7 of each 32-lane item group emit that item's 8 logits
    if (l32 < 8) out[b * 8 + row] = osum;
}

extern "C" void kernel_launch(void* const* d_in, const int* in_sizes, int n_in,
                              void* d_out, int out_size, void* d_ws, size_t ws_size,
                              hipStream_t stream) {
    const float* S   = (const float*)d_in[0];
    const float* Wh  = (const float*)d_in[1];
    const float* bh  = (const float*)d_in[2];
    const float* Wr  = (const float*)d_in[3];
    const float* Wq  = (const float*)d_in[4];
    const float* w   = (const float*)d_in[5];
    const float* Wfc = (const float*)d_in[6];
    float* out = (float*)d_out;
    float* ws  = (float*)d_ws;

    const int B = in_sizes[0] / ROW;

    weff_kernel<<<1, 640, 0, stream>>>(Wh, bh, Wr, ws);

    // 4 waves/block, 2 items/wave => 8 items per block.
    const int grid = (B + 7) / 8;
    vin_kernel<<<grid, 256, 0, stream>>>(S, Wq, w, Wfc, ws, out, B);
}